// Round 1
// baseline (445.224 us; speedup 1.0000x reference)
//
#include <hip/hip_runtime.h>
#include <hip/hip_bf16.h>
#include <math.h>

#define N_USERS 100000
#define N_ITEMS 50000
#define N_NODES 150000
#define N_EDGES 1000000
#define N_KEYS  (2 * N_NODES)      // row keys [0,N), col keys [N,2N)
#define N_XCD   8
#define N_GU_FLAT (N_USERS * 64)   // 6,400,000
#define N_ALL_FLAT (N_NODES * 64)  // 9,600,000
#define SCAN_BLK 512
#define N_SCAN_BLOCKS ((N_KEYS + SCAN_BLK - 1) / SCAN_BLK)

typedef __hip_bfloat16 bf16;
typedef unsigned short ushort_t;
typedef unsigned int uint_t;

__device__ __forceinline__ ushort_t f2bs(float f) {
    bf16 h = __float2bfloat16(f);
    return *reinterpret_cast<ushort_t*>(&h);
}
__device__ __forceinline__ float lo2f(uint_t u) {  // low bf16 of a packed pair
    float f; *reinterpret_cast<uint_t*>(&f) = u << 16; return f;
}
__device__ __forceinline__ float hi2f(uint_t u) {  // high bf16 of a packed pair
    float f; *reinterpret_cast<uint_t*>(&f) = u & 0xFFFF0000u; return f;
}
__device__ __forceinline__ uint_t pack2(float a, float b) {
    return (uint_t)f2bs(a) | ((uint_t)f2bs(b) << 16);
}

// edge record (16B): x=src, y=pad, z=bf16{w0,w1}, w=bf16{w2,w3}
// (w fields consumed only by degdis; agg recomputes norm from dis on the fly)

// ---------- Phase 1 (fused): XCD-local rank atomics || Gu/Gi -> bf16 xG ----------
// Per-XCD private histograms cntx[xcd][key]; workgroup-scope atomics stay in the
// XCD's own L2 (correct: all updates to copy x come from blocks physically on XCD x,
// which share that L2; cross-kernel visibility via end-of-dispatch release).
__global__ __launch_bounds__(256) void dg_hist_cast(
        const int* __restrict__ ei,
        const float* __restrict__ Gu, const float* __restrict__ Gi, ushort_t* __restrict__ xG,
        ushort_t* __restrict__ rank_r, ushort_t* __restrict__ rank_c,
        int* __restrict__ cntx, int gE) {
    int b = blockIdx.x;
    if (b >= gE) {
        long base = ((long)(b - gE) * 256 + threadIdx.x) * 4;
        if (base >= N_ALL_FLAT) return;
        float4 v = (base < N_GU_FLAT) ? *(const float4*)(Gu + base)
                                      : *(const float4*)(Gi + (base - N_GU_FLAT));
        uint2 o;
        o.x = pack2(v.x, v.y);
        o.y = pack2(v.z, v.w);
        *(uint2*)(xG + base) = o;
        return;
    }
    int e = b * 256 + threadIdx.x;
    if (e >= N_EDGES) return;
    uint_t xcd;
    asm("s_getreg_b32 %0, hwreg(HW_REG_XCC_ID)" : "=s"(xcd));
    xcd &= 7;
    int* cbase = cntx + (size_t)xcd * N_KEYS;
    int r = ei[e];
    int c = ei[N_EDGES + e];
    uint_t lr = (uint_t)__hip_atomic_fetch_add(&cbase[r], 1,
                    __ATOMIC_RELAXED, __HIP_MEMORY_SCOPE_WORKGROUP);
    uint_t lc = (uint_t)__hip_atomic_fetch_add(&cbase[N_NODES + c], 1,
                    __ATOMIC_RELAXED, __HIP_MEMORY_SCOPE_WORKGROUP);
    rank_r[e] = (ushort_t)(lr | (xcd << 12));   // 12-bit local rank, 3-bit xcd
    rank_c[e] = (ushort_t)(lc | (xcd << 12));
}

// ---------- Phase 2: fold 8 histograms -> totals + per-XCD bases; scan totals ----------
__global__ void dg_scan1(const int* __restrict__ cntx, int* __restrict__ cnt_tot,
                         int* __restrict__ offs, int* __restrict__ offsx,
                         int* __restrict__ partials) {
    __shared__ int s[SCAN_BLK];
    int t = threadIdx.x;
    int i = blockIdx.x * SCAN_BLK + t;
    int v = 0;
    if (i < N_KEYS) {
        int acc = 0;
        int bx[N_XCD];
        #pragma unroll
        for (int x = 0; x < N_XCD; ++x) {
            bx[x] = acc;
            acc += cntx[(size_t)x * N_KEYS + i];
        }
        v = acc;
        cnt_tot[i] = v;
        int4* o = (int4*)(offsx + (size_t)i * 8);
        o[0] = make_int4(bx[0], bx[1], bx[2], bx[3]);
        o[1] = make_int4(bx[4], bx[5], bx[6], bx[7]);
    }
    s[t] = v;
    __syncthreads();
    for (int off = 1; off < SCAN_BLK; off <<= 1) {
        int a = (t >= off) ? s[t - off] : 0;
        __syncthreads();
        s[t] += a;
        __syncthreads();
    }
    int incl = s[t];
    if (i < N_KEYS) offs[i] = incl - v;
    if (t == SCAN_BLK - 1) partials[blockIdx.x] = incl;
}

__global__ void dg_scan2(int* __restrict__ partials) {
    __shared__ int s[1024];
    int t = threadIdx.x;
    int v = (t < N_SCAN_BLOCKS) ? partials[t] : 0;
    s[t] = v;
    __syncthreads();
    for (int off = 1; off < 1024; off <<= 1) {
        int a = (t >= off) ? s[t - off] : 0;
        __syncthreads();
        s[t] += a;
        __syncthreads();
    }
    if (t < N_SCAN_BLOCKS) partials[t] = (t > 0) ? s[t - 1] : 0;
}

__global__ void dg_scan3(int* __restrict__ offs, int* __restrict__ offsx,
                         const int* __restrict__ partials) {
    int i = blockIdx.x * SCAN_BLK + threadIdx.x;
    if (i >= N_KEYS) return;
    int fin = offs[i] + partials[blockIdx.x];
    offs[i] = fin;
    int4* o = (int4*)(offsx + (size_t)i * 8);
    int4 a = o[0], b = o[1];
    a.x += fin; a.y += fin; a.z += fin; a.w += fin;
    b.x += fin; b.y += fin; b.z += fin; b.w += fin;
    o[0] = a; o[1] = b;
}

// ---------- Phase 3: deterministic scatter; softmax recomputed here (no atomics) ----------
__global__ __launch_bounds__(256) void dg_scatter(
        const int* __restrict__ ei, const float* __restrict__ intents,
        const ushort_t* __restrict__ rank_r, const ushort_t* __restrict__ rank_c,
        const int* __restrict__ offsx, uint2* __restrict__ row_w8,
        uint4* __restrict__ rec) {
    int e = blockIdx.x * blockDim.x + threadIdx.x;
    if (e >= N_EDGES) return;
    float v0 = intents[e];
    float v1 = intents[N_EDGES + e];
    float v2 = intents[2 * N_EDGES + e];
    float v3 = intents[3 * N_EDGES + e];
    float m  = fmaxf(fmaxf(v0, v1), fmaxf(v2, v3));
    float e0 = __expf(v0 - m), e1 = __expf(v1 - m), e2 = __expf(v2 - m), e3 = __expf(v3 - m);
    float inv = 1.0f / (e0 + e1 + e2 + e3);
    uint_t wlo = pack2(e0 * inv, e1 * inv);
    uint_t whi = pack2(e2 * inv, e3 * inv);
    int r = ei[e];
    int c = ei[N_EDGES + e];
    int pkr = rank_r[e];
    int pr = offsx[(size_t)r * 8 + (pkr >> 12)] + (pkr & 0xFFF);
    uint2 wp; wp.x = wlo; wp.y = whi;
    row_w8[pr] = wp;
    int pkc = rank_c[e];
    int pc = offsx[(size_t)(N_NODES + c) * 8 + (pkc >> 12)] + (pkc & 0xFFF) - N_EDGES;
    uint4 rc; rc.x = (uint_t)r; rc.y = 0u; rc.z = wlo; rc.w = whi;
    rec[pc] = rc;
}

// ---------- Phase 4: deg = streaming bf16 sums over both CSR segments -> dis ----------
__global__ void dg_degdis(const int* __restrict__ cnt_tot, const int* __restrict__ offs,
                          const uint_t* __restrict__ row_w8, const uint_t* __restrict__ rec_u,
                          float* __restrict__ dis) {
    int t = blockIdx.x * blockDim.x + threadIdx.x;  // (node, k)
    if (t >= N_NODES * 4) return;
    int n = t >> 2, k = t & 3;
    int hw = k >> 1, odd = k & 1;
    float d = 0.f;
    int o = offs[n], c = cnt_tot[n];
    for (int i = 0; i < c; ++i) {
        uint_t u = row_w8[(long)(o + i) * 2 + hw];
        d += odd ? hi2f(u) : lo2f(u);
    }
    o = offs[N_NODES + n] - N_EDGES; c = cnt_tot[N_NODES + n];
    for (int i = 0; i < c; ++i) {
        uint_t u = rec_u[(long)(o + i) * 4 + 2 + hw];
        d += odd ? hi2f(u) : lo2f(u);
    }
    dis[t] = (d > 0.f) ? rsqrtf(fmaxf(d, 1e-12f)) : 0.f;
}

// ---------- Phase 5: aggregation — 8 edges/wave-iter, norm computed on the fly ----------
// lanes: g = lane>>3 (edge subgroup), j = lane&7 (comps 8j..8j+7, intent k = j>>1)
template <int LAST>
__global__ __launch_bounds__(256) void dg_agg(const ushort_t* __restrict__ xin,
                                              ushort_t* __restrict__ xout_b,
                                              float* __restrict__ xout_f,
                                              const int* __restrict__ rec_src,
                                              const int* __restrict__ cnt_tot,
                                              const int* __restrict__ offs,
                                              const float* __restrict__ dis) {
    int wid  = (blockIdx.x * blockDim.x + threadIdx.x) >> 6;
    int lane = threadIdx.x & 63;
    if (wid >= N_NODES) return;
    int base = offs[N_NODES + wid] - N_EDGES;
    int cnt  = cnt_tot[N_NODES + wid];
    int g = lane >> 3, j = lane & 7, k = j >> 1;
    float dn = dis[wid * 4 + k];
    float a0 = 0.f, a1 = 0.f, a2 = 0.f, a3 = 0.f;
    float a4 = 0.f, a5 = 0.f, a6 = 0.f, a7 = 0.f;
    for (int i = 0; i < cnt; i += 8) {
        int ii = i + g;
        bool valid = ii < cnt;
        long idx = base + (valid ? ii : cnt - 1);
        int src = rec_src[idx * 4];                    // rec stride 16B; broadcast per subgroup
        float nk = valid ? dis[(long)src * 4 + k] * dn : 0.f;  // f32 norm, L2-resident gather
        uint4 xu = *(const uint4*)(xin + (long)src * 64 + j * 8);  // 16B/lane, 1KB/wave
        a0 = fmaf(nk, lo2f(xu.x), a0);
        a1 = fmaf(nk, hi2f(xu.x), a1);
        a2 = fmaf(nk, lo2f(xu.y), a2);
        a3 = fmaf(nk, hi2f(xu.y), a3);
        a4 = fmaf(nk, lo2f(xu.z), a4);
        a5 = fmaf(nk, hi2f(xu.z), a5);
        a6 = fmaf(nk, lo2f(xu.w), a6);
        a7 = fmaf(nk, hi2f(xu.w), a7);
    }
    // reduce the 8 edge subgroups (xor 8,16,32 over lanes)
    a0 += __shfl_xor(a0, 8); a0 += __shfl_xor(a0, 16); a0 += __shfl_xor(a0, 32);
    a1 += __shfl_xor(a1, 8); a1 += __shfl_xor(a1, 16); a1 += __shfl_xor(a1, 32);
    a2 += __shfl_xor(a2, 8); a2 += __shfl_xor(a2, 16); a2 += __shfl_xor(a2, 32);
    a3 += __shfl_xor(a3, 8); a3 += __shfl_xor(a3, 16); a3 += __shfl_xor(a3, 32);
    a4 += __shfl_xor(a4, 8); a4 += __shfl_xor(a4, 16); a4 += __shfl_xor(a4, 32);
    a5 += __shfl_xor(a5, 8); a5 += __shfl_xor(a5, 16); a5 += __shfl_xor(a5, 32);
    a6 += __shfl_xor(a6, 8); a6 += __shfl_xor(a6, 16); a6 += __shfl_xor(a6, 32);
    a7 += __shfl_xor(a7, 8); a7 += __shfl_xor(a7, 16); a7 += __shfl_xor(a7, 32);
    if (g == 0) {
        long o = (long)wid * 64 + j * 8;
        if (LAST) {
            *(float4*)(xout_f + o)     = make_float4(a0, a1, a2, a3);
            *(float4*)(xout_f + o + 4) = make_float4(a4, a5, a6, a7);
        } else {
            uint4 ob;
            ob.x = pack2(a0, a1); ob.y = pack2(a2, a3);
            ob.z = pack2(a4, a5); ob.w = pack2(a6, a7);
            *(uint4*)(xout_b + o) = ob;                // 16B/lane, 128B/node
        }
    }
}

extern "C" void kernel_launch(void* const* d_in, const int* in_sizes, int n_in,
                              void* d_out, int out_size, void* d_ws, size_t ws_size,
                              hipStream_t stream) {
    const float* Gu      = (const float*)d_in[0];   // [100000, 64] f32
    const float* Gi      = (const float*)d_in[1];   // [50000, 64]  f32
    const int*   ei      = (const int*)d_in[2];     // [2, 1000000] int32
    const float* intents = (const float*)d_in[3];   // [4, 1000000] f32
    float* out = (float*)d_out;                      // [150000, 4, 16] f32

    // ---- workspace layout (~91 MB, same footprint as before) ----
    char* ws = (char*)d_ws;
    size_t off = 0;
    uint2* row_w8 = (uint2*)(ws + off);  off += (size_t)N_EDGES * 8;    // 8 MB
    ushort_t* rank_r = (ushort_t*)(ws + off); off += (size_t)N_EDGES * 2;
    ushort_t* rank_c = (ushort_t*)(ws + off); off += (size_t)N_EDGES * 2;
    uint4* rec = (uint4*)(ws + off);     off += (size_t)N_EDGES * 16;   // 16 MB
    int* cnt_tot = (int*)(ws + off);     off += (size_t)N_KEYS * 4;
    int* offs = (int*)(ws + off);        off += (size_t)N_KEYS * 4;
    int* partials = (int*)(ws + off);    off += 4096;
    float* dis = (float*)(ws + off);     off += (size_t)N_NODES * 4 * 4;
    ushort_t* xG = (ushort_t*)(ws + off); off += (size_t)N_ALL_FLAT * 2;  // 19.2 MB
    ushort_t* xA = (ushort_t*)(ws + off); off += (size_t)N_ALL_FLAT * 2;  // 19.2 MB
    ushort_t* xB = (ushort_t*)(ws + off); off += (size_t)N_ALL_FLAT * 2;  // 19.2 MB
    // aliases: cntx dead after dg_scan1, xA first written at agg pass 1;
    //          offsx dead after dg_scatter, xB first written at agg pass 2.
    int* cntx  = (int*)xA;   // [8][N_KEYS] = 9.6 MB
    int* offsx = (int*)xB;   // [N_KEYS][8] = 9.6 MB
    (void)ws_size; (void)in_sizes; (void)n_in; (void)out_size;

    hipMemsetAsync(cntx, 0, (size_t)N_XCD * N_KEYS * sizeof(int), stream);

    const int BLK = 256;
    int gE = (N_EDGES + BLK - 1) / BLK;                 // 3907 edge blocks
    int gC = (N_ALL_FLAT / 4 + BLK - 1) / BLK;          // 9375 cast blocks

    dg_hist_cast<<<gE + gC, BLK, 0, stream>>>(ei, Gu, Gi, xG, rank_r, rank_c, cntx, gE);
    dg_scan1<<<N_SCAN_BLOCKS, SCAN_BLK, 0, stream>>>(cntx, cnt_tot, offs, offsx, partials);
    dg_scan2<<<1, 1024, 0, stream>>>(partials);
    dg_scan3<<<N_SCAN_BLOCKS, SCAN_BLK, 0, stream>>>(offs, offsx, partials);
    dg_scatter<<<gE, BLK, 0, stream>>>(ei, intents, rank_r, rank_c, offsx, row_w8, rec);
    dg_degdis<<<(N_NODES * 4 + BLK - 1) / BLK, BLK, 0, stream>>>(
        cnt_tot, offs, (const uint_t*)row_w8, (const uint_t*)rec, dis);

    int gN = (N_NODES * 64 + BLK - 1) / BLK;  // one 64-lane wave per node
    dg_agg<0><<<gN, BLK, 0, stream>>>(xG, xA, nullptr, (const int*)rec, cnt_tot, offs, dis);
    dg_agg<0><<<gN, BLK, 0, stream>>>(xA, xB, nullptr, (const int*)rec, cnt_tot, offs, dis);
    dg_agg<1><<<gN, BLK, 0, stream>>>(xB, nullptr, out, (const int*)rec, cnt_tot, offs, dis);
}

// Round 2
// 388.755 us; speedup vs baseline: 1.1453x; 1.1453x over previous
//
#include <hip/hip_runtime.h>
#include <hip/hip_bf16.h>
#include <hip/hip_fp16.h>
#include <math.h>

#define N_USERS 100000
#define N_ITEMS 50000
#define N_NODES 150000
#define N_EDGES 1000000
#define N_GU_FLAT (N_USERS * 64)   // 6,400,000
#define N_ALL_FLAT (N_NODES * 64)  // 9,600,000
#define NBUCK 586                  // node>>8 buckets, 0..585
#define HPITCH (2 * NBUCK)         // 1172 (col hist | row hist)
#define EPB 8192                   // edges per S1/S3 block
#define NEB ((N_EDGES + EPB - 1) / EPB)  // 123

typedef __hip_bfloat16 bf16;
typedef unsigned short ushort_t;
typedef unsigned int uint_t;
typedef unsigned long long u64_t;

__device__ __forceinline__ ushort_t f2bs(float f) {
    bf16 h = __float2bfloat16(f);
    return *reinterpret_cast<ushort_t*>(&h);
}
__device__ __forceinline__ float lo2f(uint_t u) {  // low bf16 of a packed pair
    float f; *reinterpret_cast<uint_t*>(&f) = u << 16; return f;
}
__device__ __forceinline__ float hi2f(uint_t u) {  // high bf16 of a packed pair
    float f; *reinterpret_cast<uint_t*>(&f) = u & 0xFFFF0000u; return f;
}
__device__ __forceinline__ uint_t pack2(float a, float b) {
    return (uint_t)f2bs(a) | ((uint_t)f2bs(b) << 16);
}
__device__ __forceinline__ ushort_t f2hs(float f) {
    __half h = __float2half(f);
    return *reinterpret_cast<ushort_t*>(&h);
}
__device__ __forceinline__ float hs2f(ushort_t u) {
    __half h; *reinterpret_cast<ushort_t*>(&h) = u;
    return __half2float(h);
}

// ---------- S1 (fused): per-block LDS bucket histograms  ||  Gu/Gi -> bf16 xG ----------
__global__ __launch_bounds__(1024) void s1_hist_cast(
        const int* __restrict__ ei,
        const float* __restrict__ Gu, const float* __restrict__ Gi,
        ushort_t* __restrict__ xG, uint_t* __restrict__ H, int gE) {
    int b = blockIdx.x;
    int t = threadIdx.x;
    if (b >= gE) {
        long base = ((long)(b - gE) * 1024 + t) * 4;
        if (base >= N_ALL_FLAT) return;
        float4 v = (base < N_GU_FLAT) ? *(const float4*)(Gu + base)
                                      : *(const float4*)(Gi + (base - N_GU_FLAT));
        uint2 o;
        o.x = pack2(v.x, v.y);
        o.y = pack2(v.z, v.w);
        *(uint2*)(xG + base) = o;
        return;
    }
    __shared__ uint_t h[HPITCH];
    for (int j = t; j < HPITCH; j += 1024) h[j] = 0;
    __syncthreads();
    int eb = b * EPB;
    int lim = min(EPB, N_EDGES - eb);
    for (int i = t; i < lim; i += 1024) {
        int e = eb + i;
        int r = ei[e];
        int c = ei[N_EDGES + e];
        atomicAdd(&h[c >> 8], 1u);
        atomicAdd(&h[NBUCK + (r >> 8)], 1u);
    }
    __syncthreads();
    for (int j = t; j < HPITCH; j += 1024) H[(size_t)b * HPITCH + j] = h[j];
}

// ---------- S2a: per-bucket scan over the 123 block histograms ----------
__global__ __launch_bounds__(128) void s2a_scan_blocks(
        const uint_t* __restrict__ H, uint_t* __restrict__ bases,
        uint_t* __restrict__ totals) {
    int j = blockIdx.x;          // 0..HPITCH-1
    int t = threadIdx.x;         // 0..127
    __shared__ uint_t s[128];
    uint_t v = (t < NEB) ? H[(size_t)t * HPITCH + j] : 0u;
    s[t] = v;
    __syncthreads();
    for (int off = 1; off < 128; off <<= 1) {
        uint_t a = (t >= off) ? s[t - off] : 0u;
        __syncthreads();
        s[t] += a;
        __syncthreads();
    }
    if (t < NEB) bases[(size_t)t * HPITCH + j] = s[t] - v;  // exclusive over blocks
    if (t == 127) totals[j] = s[127];
}

// ---------- S2b: exclusive scan of bucket totals (col and row segments) ----------
__global__ __launch_bounds__(1024) void s2b_bucket_scan(
        const uint_t* __restrict__ totals,
        uint_t* __restrict__ col_base, uint_t* __restrict__ row_base) {
    __shared__ uint_t s[1024];
    int t = threadIdx.x;
    uint_t v = (t < NBUCK) ? totals[t] : 0u;
    s[t] = v;
    __syncthreads();
    for (int off = 1; off < 1024; off <<= 1) {
        uint_t a = (t >= off) ? s[t - off] : 0u;
        __syncthreads();
        s[t] += a;
        __syncthreads();
    }
    if (t < NBUCK) col_base[t] = s[t] - v;
    if (t == NBUCK - 1) col_base[NBUCK] = s[t];
    __syncthreads();
    uint_t w = (t < NBUCK) ? totals[NBUCK + t] : 0u;
    s[t] = w;
    __syncthreads();
    for (int off = 1; off < 1024; off <<= 1) {
        uint_t a = (t >= off) ? s[t - off] : 0u;
        __syncthreads();
        s[t] += a;
        __syncthreads();
    }
    if (t < NBUCK) row_base[t] = s[t] - w;
    if (t == NBUCK - 1) row_base[NBUCK] = s[t];
}

// ---------- S3: softmax + bucketed scatter via LDS returning atomics ----------
// col record (16B): x = (node_local<<24)|src, y = bf16{w0,w1}, z = bf16{w2,w3}, w = 0
// row record (8B):  bits[0:48) = fp16{w0,w1,w2}, bits[48:56) = node_local  (w3 = 1-sum)
__global__ __launch_bounds__(1024) void s3_scatter(
        const int* __restrict__ ei, const float* __restrict__ intents,
        const uint_t* __restrict__ bases,
        const uint_t* __restrict__ col_base, const uint_t* __restrict__ row_base,
        uint4* __restrict__ tmp_col, u64_t* __restrict__ tmp_row) {
    int b = blockIdx.x, t = threadIdx.x;
    __shared__ uint_t ctr[HPITCH];
    for (int j = t; j < HPITCH; j += 1024) {
        uint_t gb = (j < NBUCK) ? col_base[j] : row_base[j - NBUCK];
        ctr[j] = gb + bases[(size_t)b * HPITCH + j];
    }
    __syncthreads();
    int eb = b * EPB;
    int lim = min(EPB, N_EDGES - eb);
    for (int i = t; i < lim; i += 1024) {
        int e = eb + i;
        int r = ei[e];
        int c = ei[N_EDGES + e];
        float v0 = intents[e];
        float v1 = intents[N_EDGES + e];
        float v2 = intents[2 * N_EDGES + e];
        float v3 = intents[3 * N_EDGES + e];
        float m  = fmaxf(fmaxf(v0, v1), fmaxf(v2, v3));
        float x0 = __expf(v0 - m), x1 = __expf(v1 - m);
        float x2 = __expf(v2 - m), x3 = __expf(v3 - m);
        float inv = 1.0f / (x0 + x1 + x2 + x3);
        float w0 = x0 * inv, w1 = x1 * inv, w2 = x2 * inv, w3 = x3 * inv;
        uint_t pc = atomicAdd(&ctr[c >> 8], 1u);
        uint4 rc;
        rc.x = ((uint_t)(c & 255) << 24) | (uint_t)r;
        rc.y = pack2(w0, w1);
        rc.z = pack2(w2, w3);
        rc.w = 0u;
        tmp_col[pc] = rc;
        uint_t pr = atomicAdd(&ctr[NBUCK + (r >> 8)], 1u);
        u64_t rw = (u64_t)f2hs(w0) | ((u64_t)f2hs(w1) << 16) |
                   ((u64_t)f2hs(w2) << 32) | ((u64_t)(uint_t)(r & 255) << 48);
        tmp_row[pr] = rw;
    }
}

// ---------- S4: per-bucket finalize — in-bucket counting sort, deg -> dis ----------
__global__ __launch_bounds__(256) void s4_finalize(
        const uint4* __restrict__ tmp_col, const u64_t* __restrict__ tmp_row,
        const uint_t* __restrict__ col_base, const uint_t* __restrict__ row_base,
        uint_t* __restrict__ rec_src, int* __restrict__ offs_c, int* __restrict__ cnt_c,
        float* __restrict__ dis) {
    int b = blockIdx.x, t = threadIdx.x;
    __shared__ uint_t hist[256], excl[256], run[256], sc[256];
    __shared__ float deg[1024];
    hist[t] = 0u; run[t] = 0u;
    deg[t] = 0.f; deg[256 + t] = 0.f; deg[512 + t] = 0.f; deg[768 + t] = 0.f;
    __syncthreads();
    uint_t c0 = col_base[b], c1 = col_base[b + 1];
    uint_t r0 = row_base[b], r1 = row_base[b + 1];
    // phase 1: col hist + col-side deg
    for (uint_t s = c0 + t; s < c1; s += 256) {
        uint4 rc = tmp_col[s];
        uint_t nl = rc.x >> 24;
        atomicAdd(&hist[nl], 1u);
        atomicAdd(&deg[nl * 4 + 0], lo2f(rc.y));
        atomicAdd(&deg[nl * 4 + 1], hi2f(rc.y));
        atomicAdd(&deg[nl * 4 + 2], lo2f(rc.z));
        atomicAdd(&deg[nl * 4 + 3], hi2f(rc.z));
    }
    // row-side deg
    for (uint_t s = r0 + t; s < r1; s += 256) {
        u64_t rw = tmp_row[s];
        uint_t nl = (uint_t)(rw >> 48) & 255u;
        float w0 = hs2f((ushort_t)(rw & 0xFFFF));
        float w1 = hs2f((ushort_t)((rw >> 16) & 0xFFFF));
        float w2 = hs2f((ushort_t)((rw >> 32) & 0xFFFF));
        float w3 = 1.0f - w0 - w1 - w2;
        atomicAdd(&deg[nl * 4 + 0], w0);
        atomicAdd(&deg[nl * 4 + 1], w1);
        atomicAdd(&deg[nl * 4 + 2], w2);
        atomicAdd(&deg[nl * 4 + 3], w3);
    }
    __syncthreads();
    // exclusive scan of hist
    sc[t] = hist[t];
    __syncthreads();
    for (int off = 1; off < 256; off <<= 1) {
        uint_t a = (t >= off) ? sc[t - off] : 0u;
        __syncthreads();
        sc[t] += a;
        __syncthreads();
    }
    excl[t] = sc[t] - hist[t];
    __syncthreads();
    // phase 3: place col records (src only) in node order
    for (uint_t s = c0 + t; s < c1; s += 256) {
        uint_t meta = tmp_col[s].x;
        uint_t nl = meta >> 24;
        uint_t p = atomicAdd(&run[nl], 1u);
        rec_src[c0 + excl[nl] + p] = meta & 0x00FFFFFFu;
    }
    // per-node outputs
    int n = b * 256 + t;
    if (n < N_NODES) {
        offs_c[n] = (int)(c0 + excl[t]);
        cnt_c[n]  = (int)hist[t];
        float d0 = deg[t * 4 + 0], d1 = deg[t * 4 + 1];
        float d2 = deg[t * 4 + 2], d3 = deg[t * 4 + 3];
        float4 dd;
        dd.x = (d0 > 0.f) ? rsqrtf(fmaxf(d0, 1e-12f)) : 0.f;
        dd.y = (d1 > 0.f) ? rsqrtf(fmaxf(d1, 1e-12f)) : 0.f;
        dd.z = (d2 > 0.f) ? rsqrtf(fmaxf(d2, 1e-12f)) : 0.f;
        dd.w = (d3 > 0.f) ? rsqrtf(fmaxf(d3, 1e-12f)) : 0.f;
        *(float4*)(dis + (size_t)n * 4) = dd;
    }
}

// ---------- agg: 8 edges/wave-iter, norm from dis on the fly ----------
// lanes: g = lane>>3 (edge subgroup), j = lane&7 (comps 8j..8j+7, intent k = j>>1)
template <int LAST>
__global__ __launch_bounds__(256) void dg_agg(const ushort_t* __restrict__ xin,
                                              ushort_t* __restrict__ xout_b,
                                              float* __restrict__ xout_f,
                                              const uint_t* __restrict__ rec_src,
                                              const int* __restrict__ cnt_c,
                                              const int* __restrict__ offs_c,
                                              const float* __restrict__ dis) {
    int wid  = (blockIdx.x * blockDim.x + threadIdx.x) >> 6;
    int lane = threadIdx.x & 63;
    if (wid >= N_NODES) return;
    int base = offs_c[wid];
    int cnt  = cnt_c[wid];
    int g = lane >> 3, j = lane & 7, k = j >> 1;
    float dn = dis[wid * 4 + k];
    float a0 = 0.f, a1 = 0.f, a2 = 0.f, a3 = 0.f;
    float a4 = 0.f, a5 = 0.f, a6 = 0.f, a7 = 0.f;
    for (int i = 0; i < cnt; i += 8) {
        int ii = i + g;
        bool valid = ii < cnt;
        int idx = base + (valid ? ii : cnt - 1);
        int src = (int)rec_src[idx];                   // 4B, consecutive across subgroups
        float nk = valid ? dis[(long)src * 4 + k] * dn : 0.f;
        uint4 xu = *(const uint4*)(xin + (long)src * 64 + j * 8);  // 16B/lane, 1KB/wave
        a0 = fmaf(nk, lo2f(xu.x), a0);
        a1 = fmaf(nk, hi2f(xu.x), a1);
        a2 = fmaf(nk, lo2f(xu.y), a2);
        a3 = fmaf(nk, hi2f(xu.y), a3);
        a4 = fmaf(nk, lo2f(xu.z), a4);
        a5 = fmaf(nk, hi2f(xu.z), a5);
        a6 = fmaf(nk, lo2f(xu.w), a6);
        a7 = fmaf(nk, hi2f(xu.w), a7);
    }
    a0 += __shfl_xor(a0, 8); a0 += __shfl_xor(a0, 16); a0 += __shfl_xor(a0, 32);
    a1 += __shfl_xor(a1, 8); a1 += __shfl_xor(a1, 16); a1 += __shfl_xor(a1, 32);
    a2 += __shfl_xor(a2, 8); a2 += __shfl_xor(a2, 16); a2 += __shfl_xor(a2, 32);
    a3 += __shfl_xor(a3, 8); a3 += __shfl_xor(a3, 16); a3 += __shfl_xor(a3, 32);
    a4 += __shfl_xor(a4, 8); a4 += __shfl_xor(a4, 16); a4 += __shfl_xor(a4, 32);
    a5 += __shfl_xor(a5, 8); a5 += __shfl_xor(a5, 16); a5 += __shfl_xor(a5, 32);
    a6 += __shfl_xor(a6, 8); a6 += __shfl_xor(a6, 16); a6 += __shfl_xor(a6, 32);
    a7 += __shfl_xor(a7, 8); a7 += __shfl_xor(a7, 16); a7 += __shfl_xor(a7, 32);
    if (g == 0) {
        long o = (long)wid * 64 + j * 8;
        if (LAST) {
            *(float4*)(xout_f + o)     = make_float4(a0, a1, a2, a3);
            *(float4*)(xout_f + o + 4) = make_float4(a4, a5, a6, a7);
        } else {
            uint4 ob;
            ob.x = pack2(a0, a1); ob.y = pack2(a2, a3);
            ob.z = pack2(a4, a5); ob.w = pack2(a6, a7);
            *(uint4*)(xout_b + o) = ob;
        }
    }
}

extern "C" void kernel_launch(void* const* d_in, const int* in_sizes, int n_in,
                              void* d_out, int out_size, void* d_ws, size_t ws_size,
                              hipStream_t stream) {
    const float* Gu      = (const float*)d_in[0];   // [100000, 64] f32
    const float* Gi      = (const float*)d_in[1];   // [50000, 64]  f32
    const int*   ei      = (const int*)d_in[2];     // [2, 1000000] int32
    const float* intents = (const float*)d_in[3];   // [4, 1000000] f32
    float* out = (float*)d_out;                      // [150000, 4, 16] f32

    // ---- workspace layout (~65 MB) ----
    char* ws = (char*)d_ws;
    size_t off = 0;
    int* offs_c = (int*)(ws + off);       off += (size_t)N_NODES * 4;          // 600 KB
    int* cnt_c  = (int*)(ws + off);       off += (size_t)N_NODES * 4;          // 600 KB
    float* dis  = (float*)(ws + off);     off += (size_t)N_NODES * 16;         // 2.4 MB
    uint_t* rec_src = (uint_t*)(ws + off); off += (size_t)N_EDGES * 4;         // 4 MB
    uint_t* col_base = (uint_t*)(ws + off); off += 4096;                       // 587 used
    uint_t* row_base = (uint_t*)(ws + off); off += 4096;
    uint_t* totals   = (uint_t*)(ws + off); off += 8192;                       // 1172 used
    ushort_t* xG = (ushort_t*)(ws + off); off += (size_t)N_ALL_FLAT * 2;       // 19.2 MB
    ushort_t* xA = (ushort_t*)(ws + off); off += (size_t)N_ALL_FLAT * 2;       // 19.2 MB
    ushort_t* xB = (ushort_t*)(ws + off); off += (size_t)N_ALL_FLAT * 2;       // 19.2 MB
    // aliases (all dead before their hosts are written):
    //   tmp_col (16 MB, dead after S4)            -> xA (first write: agg pass 1)
    //   tmp_row (8 MB) + H + bases (dead after S4) -> xB (first write: agg pass 2)
    uint4* tmp_col = (uint4*)xA;
    u64_t* tmp_row = (u64_t*)xB;
    uint_t* H     = (uint_t*)((char*)xB + 8000000);                    // 123*1172*4 = 576,624
    uint_t* bases = (uint_t*)((char*)xB + 8000000 + 576640);           // same size
    (void)ws_size; (void)in_sizes; (void)n_in; (void)out_size;

    const int gE1 = NEB;                                    // 123 edge blocks
    const int gC1 = (N_ALL_FLAT / 4 + 1023) / 1024;         // 2344 cast blocks

    s1_hist_cast<<<gE1 + gC1, 1024, 0, stream>>>(ei, Gu, Gi, xG, H, gE1);
    s2a_scan_blocks<<<HPITCH, 128, 0, stream>>>(H, bases, totals);
    s2b_bucket_scan<<<1, 1024, 0, stream>>>(totals, col_base, row_base);
    s3_scatter<<<NEB, 1024, 0, stream>>>(ei, intents, bases, col_base, row_base,
                                         tmp_col, tmp_row);
    s4_finalize<<<NBUCK, 256, 0, stream>>>(tmp_col, tmp_row, col_base, row_base,
                                           rec_src, offs_c, cnt_c, dis);

    int gN = (N_NODES * 64 + 255) / 256;  // one 64-lane wave per node
    dg_agg<0><<<gN, 256, 0, stream>>>(xG, xA, nullptr, rec_src, cnt_c, offs_c, dis);
    dg_agg<0><<<gN, 256, 0, stream>>>(xA, xB, nullptr, rec_src, cnt_c, offs_c, dis);
    dg_agg<1><<<gN, 256, 0, stream>>>(xB, nullptr, out, rec_src, cnt_c, offs_c, dis);
}

// Round 3
// 273.072 us; speedup vs baseline: 1.6304x; 1.4236x over previous
//
#include <hip/hip_runtime.h>
#include <hip/hip_bf16.h>
#include <hip/hip_fp16.h>
#include <math.h>

#define N_USERS 100000
#define N_ITEMS 50000
#define N_NODES 150000
#define N_EDGES 1000000
#define N_GU_FLAT (N_USERS * 64)   // 6,400,000
#define N_ALL_FLAT (N_NODES * 64)  // 9,600,000
#define NBUCK 586                  // node>>8 buckets
#define HPITCH (2 * NBUCK)         // 1172 (col | row)
#define EPB 4096                   // edges per S1/S3 block
#define NEB ((N_EDGES + EPB - 1) / EPB)  // 245

typedef __hip_bfloat16 bf16;
typedef unsigned short ushort_t;
typedef unsigned int uint_t;
typedef unsigned long long u64_t;

__device__ __forceinline__ ushort_t f2bs(float f) {
    bf16 h = __float2bfloat16(f);
    return *reinterpret_cast<ushort_t*>(&h);
}
__device__ __forceinline__ float lo2f(uint_t u) {
    float f; *reinterpret_cast<uint_t*>(&f) = u << 16; return f;
}
__device__ __forceinline__ float hi2f(uint_t u) {
    float f; *reinterpret_cast<uint_t*>(&f) = u & 0xFFFF0000u; return f;
}
__device__ __forceinline__ uint_t pack2(float a, float b) {
    return (uint_t)f2bs(a) | ((uint_t)f2bs(b) << 16);
}
__device__ __forceinline__ ushort_t f2hs(float f) {
    __half h = __float2half(f);
    return *reinterpret_cast<ushort_t*>(&h);
}
__device__ __forceinline__ float hs2f(ushort_t u) {
    __half h; *reinterpret_cast<ushort_t*>(&h) = u;
    return __half2float(h);
}

// ---------- S1 (fused): per-block LDS bucket histograms  ||  Gu/Gi -> bf16 xG ----------
__global__ __launch_bounds__(1024) void s1_hist_cast(
        const int* __restrict__ ei,
        const float* __restrict__ Gu, const float* __restrict__ Gi,
        ushort_t* __restrict__ xG, uint_t* __restrict__ H, int gE) {
    int b = blockIdx.x;
    int t = threadIdx.x;
    if (b >= gE) {
        long base = ((long)(b - gE) * 1024 + t) * 4;
        if (base >= N_ALL_FLAT) return;
        float4 v = (base < N_GU_FLAT) ? *(const float4*)(Gu + base)
                                      : *(const float4*)(Gi + (base - N_GU_FLAT));
        uint2 o;
        o.x = pack2(v.x, v.y);
        o.y = pack2(v.z, v.w);
        *(uint2*)(xG + base) = o;
        return;
    }
    __shared__ uint_t h[HPITCH];
    for (int j = t; j < HPITCH; j += 1024) h[j] = 0;
    __syncthreads();
    int eb = b * EPB;
    int lim = min(EPB, N_EDGES - eb);
    for (int i = t; i < lim; i += 1024) {
        int e = eb + i;
        int r = ei[e];
        int c = ei[N_EDGES + e];
        atomicAdd(&h[c >> 8], 1u);
        atomicAdd(&h[NBUCK + (r >> 8)], 1u);
    }
    __syncthreads();
    for (int j = t; j < HPITCH; j += 1024) H[(size_t)b * HPITCH + j] = h[j];
}

// ---------- S2a: per-bucket exclusive scan over the 245 block histograms ----------
__global__ __launch_bounds__(256) void s2a_scan_blocks(
        const uint_t* __restrict__ H, uint_t* __restrict__ bases,
        uint_t* __restrict__ totals) {
    int j = blockIdx.x;          // 0..HPITCH-1
    int t = threadIdx.x;         // 0..255
    __shared__ uint_t s[256];
    uint_t v = (t < NEB) ? H[(size_t)t * HPITCH + j] : 0u;
    s[t] = v;
    __syncthreads();
    for (int off = 1; off < 256; off <<= 1) {
        uint_t a = (t >= off) ? s[t - off] : 0u;
        __syncthreads();
        s[t] += a;
        __syncthreads();
    }
    if (t < NEB) bases[(size_t)t * HPITCH + j] = s[t] - v;
    if (t == 255) totals[j] = s[255];
}

// ---------- S2b: exclusive scan of bucket totals (col and row segments) ----------
__global__ __launch_bounds__(1024) void s2b_bucket_scan(
        const uint_t* __restrict__ totals,
        uint_t* __restrict__ col_base, uint_t* __restrict__ row_base) {
    __shared__ uint_t s[1024];
    int t = threadIdx.x;
    uint_t v = (t < NBUCK) ? totals[t] : 0u;
    s[t] = v;
    __syncthreads();
    for (int off = 1; off < 1024; off <<= 1) {
        uint_t a = (t >= off) ? s[t - off] : 0u;
        __syncthreads();
        s[t] += a;
        __syncthreads();
    }
    if (t < NBUCK) col_base[t] = s[t] - v;
    if (t == NBUCK - 1) col_base[NBUCK] = s[t];
    __syncthreads();
    uint_t w = (t < NBUCK) ? totals[NBUCK + t] : 0u;
    s[t] = w;
    __syncthreads();
    for (int off = 1; off < 1024; off <<= 1) {
        uint_t a = (t >= off) ? s[t - off] : 0u;
        __syncthreads();
        s[t] += a;
        __syncthreads();
    }
    if (t < NBUCK) row_base[t] = s[t] - w;
    if (t == NBUCK - 1) row_base[NBUCK] = s[t];
}

// ---------- S3: softmax + in-LDS bucket sort, coalesced flush ----------
// col record (16B): x = (node_local<<24)|src, y = bf16{w0,w1}, z = bf16{w2,w3}, w = global pos
// row record (8B):  bits[0:48) = fp16{w0,w1,w2}, bits[48:56) = node_local  (w3 = 1-sum)
// dynamic LDS layout (128,160 B total):
//   [0)       colbuf  uint4[4096]  65536
//   [65536)   rowbuf  u64  [4096]  32768
//   [98304)   rowpos  uint [4096]  16384
//   [114688)  ctr     uint [1172]   4688
//   [119376)  lexcl   uint [1172]   4688
//   [124064)  stmp    uint [1024]   4096
__global__ __launch_bounds__(1024) void s3_scatter(
        const int* __restrict__ ei, const float* __restrict__ intents,
        const uint_t* __restrict__ bases,
        const uint_t* __restrict__ col_base, const uint_t* __restrict__ row_base,
        uint4* __restrict__ tmp_col, u64_t* __restrict__ tmp_row) {
    extern __shared__ char smem[];
    uint4*  colbuf = (uint4*)smem;
    u64_t*  rowbuf = (u64_t*)(smem + 65536);
    uint_t* rowpos = (uint_t*)(smem + 98304);
    uint_t* ctr    = (uint_t*)(smem + 114688);
    uint_t* lexcl  = (uint_t*)(smem + 119376);
    uint_t* stmp   = (uint_t*)(smem + 124064);
    int b = blockIdx.x, t = threadIdx.x;
    for (int j = t; j < HPITCH; j += 1024) ctr[j] = 0;
    __syncthreads();
    int eb = b * EPB;
    int lim = min(EPB, N_EDGES - eb);
    // phase A: 4 edges/thread (static unroll), softmax, local ranks
    int  jcol[4], jrow[4];
    uint_t rkc[4], rkr[4], meta[4], wlo[4], whi[4];
    u64_t rwv[4];
    bool val[4];
#pragma unroll
    for (int q = 0; q < 4; ++q) {
        int i = t + q * 1024;
        val[q] = (i < lim);
        int e = eb + (val[q] ? i : 0);
        int r = ei[e];
        int c = ei[N_EDGES + e];
        float v0 = intents[e];
        float v1 = intents[N_EDGES + e];
        float v2 = intents[2 * N_EDGES + e];
        float v3 = intents[3 * N_EDGES + e];
        float m  = fmaxf(fmaxf(v0, v1), fmaxf(v2, v3));
        float x0 = __expf(v0 - m), x1 = __expf(v1 - m);
        float x2 = __expf(v2 - m), x3 = __expf(v3 - m);
        float inv = 1.0f / (x0 + x1 + x2 + x3);
        float w0 = x0 * inv, w1 = x1 * inv, w2 = x2 * inv, w3 = x3 * inv;
        jcol[q] = c >> 8;
        jrow[q] = r >> 8;
        if (val[q]) {
            rkc[q] = atomicAdd(&ctr[jcol[q]], 1u);
            rkr[q] = atomicAdd(&ctr[NBUCK + jrow[q]], 1u);
        }
        meta[q] = ((uint_t)(c & 255) << 24) | (uint_t)r;
        wlo[q]  = pack2(w0, w1);
        whi[q]  = pack2(w2, w3);
        rwv[q]  = (u64_t)f2hs(w0) | ((u64_t)f2hs(w1) << 16) |
                  ((u64_t)f2hs(w2) << 32) | ((u64_t)(uint_t)(r & 255) << 48);
    }
    __syncthreads();
    // phase B: local exclusive scans (col, then row)
    {
        uint_t v = (t < NBUCK) ? ctr[t] : 0u;
        stmp[t] = v;
        __syncthreads();
        for (int off = 1; off < 1024; off <<= 1) {
            uint_t a = (t >= off) ? stmp[t - off] : 0u;
            __syncthreads();
            stmp[t] += a;
            __syncthreads();
        }
        if (t < NBUCK) lexcl[t] = stmp[t] - v;
    }
    __syncthreads();
    {
        uint_t v = (t < NBUCK) ? ctr[NBUCK + t] : 0u;
        stmp[t] = v;
        __syncthreads();
        for (int off = 1; off < 1024; off <<= 1) {
            uint_t a = (t >= off) ? stmp[t - off] : 0u;
            __syncthreads();
            stmp[t] += a;
            __syncthreads();
        }
        if (t < NBUCK) lexcl[NBUCK + t] = stmp[t] - v;
    }
    __syncthreads();
    // phase C: place records into LDS in bucket order; stash global pos
#pragma unroll
    for (int q = 0; q < 4; ++q) {
        if (!val[q]) continue;
        uint_t lp = lexcl[jcol[q]] + rkc[q];
        uint_t pc = col_base[jcol[q]] + bases[(size_t)b * HPITCH + jcol[q]] + rkc[q];
        colbuf[lp] = make_uint4(meta[q], wlo[q], whi[q], pc);
        uint_t lr = lexcl[NBUCK + jrow[q]] + rkr[q];
        rowbuf[lr] = rwv[q];
        rowpos[lr] = row_base[jrow[q]] + bases[(size_t)b * HPITCH + NBUCK + jrow[q]] + rkr[q];
    }
    __syncthreads();
    // phase D: sequential flush -> coalesced runs per bucket
    for (int i = t; i < lim; i += 1024) {
        uint4 rc = colbuf[i];
        tmp_col[rc.w] = rc;           // .w = pos (ignored downstream)
        tmp_row[rowpos[i]] = rowbuf[i];
    }
}

// ---------- S4: per-bucket finalize — in-bucket counting sort, deg -> dis ----------
__global__ __launch_bounds__(256) void s4_finalize(
        const uint4* __restrict__ tmp_col, const u64_t* __restrict__ tmp_row,
        const uint_t* __restrict__ col_base, const uint_t* __restrict__ row_base,
        uint_t* __restrict__ rec_src, int* __restrict__ offs_c, int* __restrict__ cnt_c,
        float* __restrict__ dis) {
    int b = blockIdx.x, t = threadIdx.x;
    __shared__ uint_t hist[256], excl[256], run[256], sc[256];
    __shared__ float deg[1024];
    hist[t] = 0u; run[t] = 0u;
    deg[t] = 0.f; deg[256 + t] = 0.f; deg[512 + t] = 0.f; deg[768 + t] = 0.f;
    __syncthreads();
    uint_t c0 = col_base[b], c1 = col_base[b + 1];
    uint_t r0 = row_base[b], r1 = row_base[b + 1];
    for (uint_t s = c0 + t; s < c1; s += 256) {
        uint4 rc = tmp_col[s];
        uint_t nl = rc.x >> 24;
        atomicAdd(&hist[nl], 1u);
        atomicAdd(&deg[nl * 4 + 0], lo2f(rc.y));
        atomicAdd(&deg[nl * 4 + 1], hi2f(rc.y));
        atomicAdd(&deg[nl * 4 + 2], lo2f(rc.z));
        atomicAdd(&deg[nl * 4 + 3], hi2f(rc.z));
    }
    for (uint_t s = r0 + t; s < r1; s += 256) {
        u64_t rw = tmp_row[s];
        uint_t nl = (uint_t)(rw >> 48) & 255u;
        float w0 = hs2f((ushort_t)(rw & 0xFFFF));
        float w1 = hs2f((ushort_t)((rw >> 16) & 0xFFFF));
        float w2 = hs2f((ushort_t)((rw >> 32) & 0xFFFF));
        float w3 = 1.0f - w0 - w1 - w2;
        atomicAdd(&deg[nl * 4 + 0], w0);
        atomicAdd(&deg[nl * 4 + 1], w1);
        atomicAdd(&deg[nl * 4 + 2], w2);
        atomicAdd(&deg[nl * 4 + 3], w3);
    }
    __syncthreads();
    sc[t] = hist[t];
    __syncthreads();
    for (int off = 1; off < 256; off <<= 1) {
        uint_t a = (t >= off) ? sc[t - off] : 0u;
        __syncthreads();
        sc[t] += a;
        __syncthreads();
    }
    excl[t] = sc[t] - hist[t];
    __syncthreads();
    for (uint_t s = c0 + t; s < c1; s += 256) {
        uint_t m = tmp_col[s].x;
        uint_t nl = m >> 24;
        uint_t p = atomicAdd(&run[nl], 1u);
        rec_src[c0 + excl[nl] + p] = m & 0x00FFFFFFu;
    }
    int n = b * 256 + t;
    if (n < N_NODES) {
        offs_c[n] = (int)(c0 + excl[t]);
        cnt_c[n]  = (int)hist[t];
        float d0 = deg[t * 4 + 0], d1 = deg[t * 4 + 1];
        float d2 = deg[t * 4 + 2], d3 = deg[t * 4 + 3];
        float4 dd;
        dd.x = (d0 > 0.f) ? rsqrtf(fmaxf(d0, 1e-12f)) : 0.f;
        dd.y = (d1 > 0.f) ? rsqrtf(fmaxf(d1, 1e-12f)) : 0.f;
        dd.z = (d2 > 0.f) ? rsqrtf(fmaxf(d2, 1e-12f)) : 0.f;
        dd.w = (d3 > 0.f) ? rsqrtf(fmaxf(d3, 1e-12f)) : 0.f;
        *(float4*)(dis + (size_t)n * 4) = dd;
    }
}

// ---------- agg: subgroup(8 lanes)-per-node; y-representation ----------
// MODE 0: in = raw x0 bf16, per-edge *dis[src]; out y1 = dis^2 * sum   (bf16)
// MODE 1: in = y bf16, pure sum;                out y2 = dis^2 * sum   (bf16)
// MODE 2: in = y bf16, pure sum;                out x3 = dis * sum     (f32)
template <int MODE>
__global__ __launch_bounds__(256) void dg_agg(const ushort_t* __restrict__ xin,
                                              ushort_t* __restrict__ xout_b,
                                              float* __restrict__ xout_f,
                                              const uint_t* __restrict__ rec_src,
                                              const int* __restrict__ cnt_c,
                                              const int* __restrict__ offs_c,
                                              const float* __restrict__ dis) {
    int n = (blockIdx.x * 256 + threadIdx.x) >> 3;
    if (n >= N_NODES) return;
    int j = threadIdx.x & 7, k = j >> 1;
    int base = offs_c[n];
    int cnt  = cnt_c[n];
    float dd = dis[n * 4 + k];
    float a0 = 0.f, a1 = 0.f, a2 = 0.f, a3 = 0.f;
    float a4 = 0.f, a5 = 0.f, a6 = 0.f, a7 = 0.f;
    int i = 0;
    for (; i + 2 <= cnt; i += 2) {
        int s0 = (int)rec_src[base + i];
        int s1 = (int)rec_src[base + i + 1];
        uint4 x0 = *(const uint4*)(xin + (long)s0 * 64 + j * 8);
        uint4 x1 = *(const uint4*)(xin + (long)s1 * 64 + j * 8);
        float n0 = 1.f, n1 = 1.f;
        if (MODE == 0) { n0 = dis[s0 * 4 + k]; n1 = dis[s1 * 4 + k]; }
        a0 = fmaf(n0, lo2f(x0.x), a0); a1 = fmaf(n0, hi2f(x0.x), a1);
        a2 = fmaf(n0, lo2f(x0.y), a2); a3 = fmaf(n0, hi2f(x0.y), a3);
        a4 = fmaf(n0, lo2f(x0.z), a4); a5 = fmaf(n0, hi2f(x0.z), a5);
        a6 = fmaf(n0, lo2f(x0.w), a6); a7 = fmaf(n0, hi2f(x0.w), a7);
        a0 = fmaf(n1, lo2f(x1.x), a0); a1 = fmaf(n1, hi2f(x1.x), a1);
        a2 = fmaf(n1, lo2f(x1.y), a2); a3 = fmaf(n1, hi2f(x1.y), a3);
        a4 = fmaf(n1, lo2f(x1.z), a4); a5 = fmaf(n1, hi2f(x1.z), a5);
        a6 = fmaf(n1, lo2f(x1.w), a6); a7 = fmaf(n1, hi2f(x1.w), a7);
    }
    if (i < cnt) {
        int s0 = (int)rec_src[base + i];
        uint4 x0 = *(const uint4*)(xin + (long)s0 * 64 + j * 8);
        float n0 = (MODE == 0) ? dis[s0 * 4 + k] : 1.f;
        a0 = fmaf(n0, lo2f(x0.x), a0); a1 = fmaf(n0, hi2f(x0.x), a1);
        a2 = fmaf(n0, lo2f(x0.y), a2); a3 = fmaf(n0, hi2f(x0.y), a3);
        a4 = fmaf(n0, lo2f(x0.z), a4); a5 = fmaf(n0, hi2f(x0.z), a5);
        a6 = fmaf(n0, lo2f(x0.w), a6); a7 = fmaf(n0, hi2f(x0.w), a7);
    }
    float sc = (MODE == 2) ? dd : dd * dd;
    a0 *= sc; a1 *= sc; a2 *= sc; a3 *= sc;
    a4 *= sc; a5 *= sc; a6 *= sc; a7 *= sc;
    long o = (long)n * 64 + j * 8;
    if (MODE == 2) {
        *(float4*)(xout_f + o)     = make_float4(a0, a1, a2, a3);
        *(float4*)(xout_f + o + 4) = make_float4(a4, a5, a6, a7);
    } else {
        uint4 ob;
        ob.x = pack2(a0, a1); ob.y = pack2(a2, a3);
        ob.z = pack2(a4, a5); ob.w = pack2(a6, a7);
        *(uint4*)(xout_b + o) = ob;
    }
}

extern "C" void kernel_launch(void* const* d_in, const int* in_sizes, int n_in,
                              void* d_out, int out_size, void* d_ws, size_t ws_size,
                              hipStream_t stream) {
    const float* Gu      = (const float*)d_in[0];   // [100000, 64] f32
    const float* Gi      = (const float*)d_in[1];   // [50000, 64]  f32
    const int*   ei      = (const int*)d_in[2];     // [2, 1000000] int32
    const float* intents = (const float*)d_in[3];   // [4, 1000000] f32
    float* out = (float*)d_out;                      // [150000, 4, 16] f32

    // ---- workspace layout (~65 MB) ----
    char* ws = (char*)d_ws;
    size_t off = 0;
    int* offs_c = (int*)(ws + off);       off += (size_t)N_NODES * 4;
    int* cnt_c  = (int*)(ws + off);       off += (size_t)N_NODES * 4;
    float* dis  = (float*)(ws + off);     off += (size_t)N_NODES * 16;
    uint_t* rec_src = (uint_t*)(ws + off); off += (size_t)N_EDGES * 4;
    uint_t* col_base = (uint_t*)(ws + off); off += 4096;
    uint_t* row_base = (uint_t*)(ws + off); off += 4096;
    uint_t* totals   = (uint_t*)(ws + off); off += 8192;
    ushort_t* xG = (ushort_t*)(ws + off); off += (size_t)N_ALL_FLAT * 2;   // 19.2 MB
    ushort_t* xA = (ushort_t*)(ws + off); off += (size_t)N_ALL_FLAT * 2;   // 19.2 MB
    ushort_t* xB = (ushort_t*)(ws + off); off += (size_t)N_ALL_FLAT * 2;   // 19.2 MB
    // aliases (dead before their hosts are first written):
    //   tmp_col (16 MB, dead after S4)                 -> xA (first write: agg pass 1)
    //   tmp_row (8 MB) + H + bases (dead after S3/S4)  -> xB (first write: agg pass 2)
    uint4* tmp_col = (uint4*)xA;
    u64_t* tmp_row = (u64_t*)xB;                                  // 8,000,000 B
    uint_t* H     = (uint_t*)((char*)xB + 8000000);               // 245*1172*4 = 1,148,560
    uint_t* bases = (uint_t*)((char*)xB + 9200000);               // 1,148,560
    (void)ws_size; (void)in_sizes; (void)n_in; (void)out_size;

    const int gE1 = NEB;                                    // 245 edge blocks
    const int gC1 = (N_ALL_FLAT / 4 + 1023) / 1024;         // 2344 cast blocks

    s1_hist_cast<<<gE1 + gC1, 1024, 0, stream>>>(ei, Gu, Gi, xG, H, gE1);
    s2a_scan_blocks<<<HPITCH, 256, 0, stream>>>(H, bases, totals);
    s2b_bucket_scan<<<1, 1024, 0, stream>>>(totals, col_base, row_base);

    const size_t S3_LDS = 128160;
    hipFuncSetAttribute((const void*)s3_scatter,
                        hipFuncAttributeMaxDynamicSharedMemorySize, (int)S3_LDS);
    s3_scatter<<<NEB, 1024, S3_LDS, stream>>>(ei, intents, bases, col_base, row_base,
                                              tmp_col, tmp_row);
    s4_finalize<<<NBUCK, 256, 0, stream>>>(tmp_col, tmp_row, col_base, row_base,
                                           rec_src, offs_c, cnt_c, dis);

    int gAgg = (N_NODES * 8 + 255) / 256;   // 8 lanes per node
    dg_agg<0><<<gAgg, 256, 0, stream>>>(xG, xA, nullptr, rec_src, cnt_c, offs_c, dis);
    dg_agg<1><<<gAgg, 256, 0, stream>>>(xA, xB, nullptr, rec_src, cnt_c, offs_c, dis);
    dg_agg<2><<<gAgg, 256, 0, stream>>>(xB, nullptr, out, rec_src, cnt_c, offs_c, dis);
}